// Round 1
// 203.058 us; speedup vs baseline: 1.0222x; 1.0222x over previous
//
#include <hip/hip_runtime.h>
#include <hip/hip_fp16.h>

#define N_NODES 100000
#define N_EDGES 1600000
#define IN_DIM 128
#define OUT_DIM 64

#define NBUCK 391       // ceil(N_NODES/256); bucket = dst >> 8
#define BIN_NBLK 800
#define BIN_CHUNK 2000  // BIN_NBLK * BIN_CHUNK == N_EDGES
// Static per-bucket capacity: Binom(1.6M, 256/1e5) = mean 4096, sigma 64.
// 4608 = mean + 8 sigma -> overflow P ~ 1e-12; region base b*MAXB is static,
// bucket_cursor[b] holds the RELATIVE count (zeroed by hipMemsetAsync).
#define MAXB 4608

#define PROJ_BLKS 1563  // ceil(N_NODES/64): 64 rows per block (4 waves x 16)
#define SORT_THREADS 1024

typedef short short8 __attribute__((ext_vector_type(8)));
typedef float f32x4 __attribute__((ext_vector_type(4)));

__device__ __forceinline__ short bf16_trunc(float x) {
  return (short)(__float_as_uint(x) >> 16);
}
__device__ __forceinline__ float bf16_tof(short s) {
  return __uint_as_float(((unsigned)(unsigned short)s) << 16);
}
__device__ __forceinline__ float edge_ex(float p) {
  float t2 = __expf(2.f * p);
  float th = 1.f - 2.f * __builtin_amdgcn_rcpf(t2 + 1.f);
  return __expf(th);
}

// ---- Fat kernel 1: bin-scatter (blocks < BIN_NBLK) + MFMA projection ----
// The two halves are data-independent; binning's scattered-write latency
// hides under the projection's MFMA + streaming phase.
__global__ __launch_bounds__(256) void fat1_kernel(
    const float* __restrict__ h_init, const float* __restrict__ W1,
    const float* __restrict__ a, const int* __restrict__ src,
    const int* __restrict__ dst, float* __restrict__ h,
    __half* __restrict__ h16, float* __restrict__ ha,
    int* __restrict__ bucket_cursor, unsigned int* __restrict__ pairs) {
  // 32 KB shared, overlaid: proj uses whi/wlo (16KB+16KB); bin uses hst/cur.
  __shared__ __align__(16) char smem[16 * 64 * 8 * 2 * sizeof(short)];

  if (blockIdx.x < BIN_NBLK) {
    // ---------------- bin-scatter branch ----------------
    int* hst = (int*)smem;
    int* cur = hst + NBUCK;
    for (int i = threadIdx.x; i < NBUCK; i += 256) hst[i] = 0;
    __syncthreads();
    int beg = blockIdx.x * BIN_CHUNK;
    int end = min(beg + BIN_CHUNK, N_EDGES);
    for (int e = beg + threadIdx.x; e < end; e += 256)
      atomicAdd(&hst[dst[e] >> 8], 1);
    __syncthreads();
    for (int i = threadIdx.x; i < NBUCK; i += 256) {
      int c = hst[i];
      // reserve a contiguous range; cursor is relative, region base static
      cur[i] = (c > 0) ? atomicAdd(&bucket_cursor[i], c) + i * MAXB : 0;
    }
    __syncthreads();
    for (int e = beg + threadIdx.x; e < end; e += 256) {
      int d = dst[e];
      int pos = atomicAdd(&cur[d >> 8], 1);
      pairs[pos] = ((unsigned int)src[e] << 8) | (unsigned int)(d & 255);
    }
    return;
  }

  // ---------------- projection branch ----------------
  int pb = blockIdx.x - BIN_NBLK;
  short* whi = (short*)smem;             // 16 * 64 * 8 shorts
  short* wlo = whi + 16 * 64 * 8;

  // stage W as bf16 hi/lo B-fragments (frag f=kc*4+ot, B[k][n]=W1[ot*16+n][k])
  for (int idx = threadIdx.x; idx < 16 * 64; idx += 256) {
    int f = idx >> 6;
    int l = idx & 63;
    int kc = f >> 2, ot = f & 3;
    const float* wsrc =
        W1 + (ot * 16 + (l & 15)) * IN_DIM + kc * 32 + (l >> 4) * 8;
    short hi[8], lo[8];
#pragma unroll
    for (int j = 0; j < 8; j++) {
      float x = wsrc[j];
      short hv = bf16_trunc(x);
      hi[j] = hv;
      lo[j] = bf16_trunc(x - bf16_tof(hv));
    }
    *(short8*)&whi[idx * 8] = *(const short8*)hi;
    *(short8*)&wlo[idx * 8] = *(const short8*)lo;
  }

  int row0 = pb * 64;
  int w = threadIdx.x >> 6;
  int l = threadIdx.x & 63;
  int m = l & 15;
  int q = l >> 4;

  int arow = row0 + w * 16 + m;
  if (arow >= N_NODES) arow = N_NODES - 1;
  const float* xsrc = h_init + (size_t)arow * IN_DIM + q * 8;

  short8 ahi[4], alo[4];
#pragma unroll
  for (int kc = 0; kc < 4; kc++) {
    float xv[8];
    *(float4*)&xv[0] = *(const float4*)(xsrc + kc * 32);
    *(float4*)&xv[4] = *(const float4*)(xsrc + kc * 32 + 4);
    short hi[8], lo[8];
#pragma unroll
    for (int j = 0; j < 8; j++) {
      short hv = bf16_trunc(xv[j]);
      hi[j] = hv;
      lo[j] = bf16_trunc(xv[j] - bf16_tof(hv));
    }
    ahi[kc] = *(const short8*)hi;
    alo[kc] = *(const short8*)lo;
  }
  __syncthreads();

  f32x4 acc[4] = {{0.f, 0.f, 0.f, 0.f},
                  {0.f, 0.f, 0.f, 0.f},
                  {0.f, 0.f, 0.f, 0.f},
                  {0.f, 0.f, 0.f, 0.f}};

#pragma unroll
  for (int kc = 0; kc < 4; kc++) {
#pragma unroll
    for (int ot = 0; ot < 4; ot++) {
      int base = (((kc << 2) | ot) * 64 + l) * 8;
      short8 bhi = *(const short8*)&whi[base];
      short8 blo = *(const short8*)&wlo[base];
      acc[ot] = __builtin_amdgcn_mfma_f32_16x16x32_bf16(ahi[kc], bhi, acc[ot],
                                                        0, 0, 0);
      acc[ot] = __builtin_amdgcn_mfma_f32_16x16x32_bf16(ahi[kc], blo, acc[ot],
                                                        0, 0, 0);
      acc[ot] = __builtin_amdgcn_mfma_f32_16x16x32_bf16(alo[kc], bhi, acc[ot],
                                                        0, 0, 0);
    }
  }

  float pa[4] = {0.f, 0.f, 0.f, 0.f};
#pragma unroll
  for (int ot = 0; ot < 4; ot++) {
    float aval = a[ot * 16 + m];
#pragma unroll
    for (int r = 0; r < 4; r++) pa[r] += acc[ot][r] * aval;
  }
  int rowb = row0 + w * 16 + q * 4;
#pragma unroll
  for (int r = 0; r < 4; r++) {
    int row = rowb + r;
    if (row < N_NODES) {
#pragma unroll
      for (int ot = 0; ot < 4; ot++) {
        h[(size_t)row * OUT_DIM + ot * 16 + m] = acc[ot][r];
        h16[(size_t)row * OUT_DIM + ot * 16 + m] = __float2half(acc[ot][r]);
      }
    }
  }
#pragma unroll
  for (int r = 0; r < 4; r++) {
    pa[r] += __shfl_xor(pa[r], 1);
    pa[r] += __shfl_xor(pa[r], 2);
    pa[r] += __shfl_xor(pa[r], 4);
    pa[r] += __shfl_xor(pa[r], 8);
  }
  if (m == 0) {
#pragma unroll
    for (int r = 0; r < 4; r++) {
      int row = rowb + r;
      if (row < N_NODES) ha[row] = pa[r];
    }
  }
}

// ---------------- Bucket sort + edge-logit precompute ----------------
// One WG per bucket (block count pinned at NBUCK=391), so use 1024 threads
// (16 waves) per block to lift occupancy ~4x: this kernel is latency-bound
// on random ha[s] reads and scattered sorted[] writes.
__global__ __launch_bounds__(SORT_THREADS) void bucket_sort_kernel(
    const unsigned int* __restrict__ pairs,
    const int* __restrict__ bucket_cursor, const float* __restrict__ ha,
    int* __restrict__ nbeg, int* __restrict__ nend, int2* __restrict__ sorted) {
  __shared__ unsigned int plds[MAXB];
  __shared__ int hist[256];
  __shared__ int excl[256];
  __shared__ float had[256];
  int b = blockIdx.x;
  int t = threadIdx.x;
  int pbeg = b * MAXB;
  int cnt = bucket_cursor[b];  // relative count

  if (t < 256) {
    int node = (b << 8) + t;
    had[t] = (node < N_NODES) ? ha[node] : 0.f;
    hist[t] = 0;
  }
  __syncthreads();

  for (int i = t; i < cnt; i += SORT_THREADS) {
    unsigned int p = pairs[pbeg + i];
    plds[i] = p;
    atomicAdd(&hist[p & 255u], 1);
  }
  __syncthreads();

  int v = 0;
  if (t < 256) {
    v = hist[t];
    excl[t] = v;
  }
  __syncthreads();
  for (int off = 1; off < 256; off <<= 1) {
    int u = (t >= off && t < 256) ? excl[t - off] : 0;
    __syncthreads();
    if (t < 256) excl[t] += u;
    __syncthreads();
  }
  if (t < 256) {
    int my_excl = excl[t] - v;
    int node = (b << 8) + t;
    if (node < N_NODES) {
      nbeg[node] = pbeg + my_excl;
      nend[node] = pbeg + my_excl + v;
    }
    hist[t] = my_excl;
  }
  __syncthreads();

  for (int i = t; i < cnt; i += SORT_THREADS) {
    unsigned int p = plds[i];
    int d = (int)(p & 255u);
    int s = (int)(p >> 8);
    int pos = atomicAdd(&hist[d], 1);
    float ex = edge_ex(had[d] - ha[s]);
    sorted[pbeg + pos] = make_int2(s << 7, __float_as_int(ex));  // byte offset
  }
}

// ---------------- Gather: out = relu(2*h[d] - (sum ex*h16[s])/den) ---------
// One wave per node; 8 subgroups x 8 lanes, 16 B fp16 per lane.
// 32-edge chunks, unroll-4 per subgroup; v_fma_mix fuses cvt+fma.
__global__ __launch_bounds__(256) void gather_kernel(
    const float* __restrict__ h, const __half* __restrict__ h16,
    const int* __restrict__ nbeg, const int* __restrict__ nend,
    const int2* __restrict__ sorted, float* __restrict__ out) {
  int wave = (blockIdx.x * 256 + threadIdx.x) >> 6;
  int lane = threadIdx.x & 63;
  if (wave >= N_NODES) return;
  int n = wave;
  int beg = nbeg[n];
  int end = nend[n];
  int g = lane >> 3;  // subgroup 0..7
  int l8 = lane & 7;  // cols [8*l8, 8*l8+8)

  // hoist epilogue hd loads to overlap gather latency
  const float4* h4 = (const float4*)h;
  float4 hd0 = h4[(size_t)n * (OUT_DIM / 4) + l8 * 2];
  float4 hd1 = h4[(size_t)n * (OUT_DIM / 4) + l8 * 2 + 1];

  const char* h16b = (const char*)h16;
  float acc[8] = {0.f, 0.f, 0.f, 0.f, 0.f, 0.f, 0.f, 0.f};
  float den = 0.f;

  for (int base = beg + g * 4; base < end; base += 32) {
    int last = end - 1;
    int2 e[4];
    float exv[4];
#pragma unroll
    for (int k = 0; k < 4; k++) {
      int i = base + k;
      e[k] = sorted[i < end ? i : last];
      exv[k] = (i < end) ? __int_as_float(e[k].y) : 0.f;
    }
    uint4 uv[4];
#pragma unroll
    for (int k = 0; k < 4; k++)
      uv[k] = *(const uint4*)(h16b + e[k].x + (l8 << 4));
#pragma unroll
    for (int k = 0; k < 4; k++) {
      union {
        uint4 u;
        __half hh[8];
      } U;
      U.u = uv[k];
      float ex = exv[k];
      den += ex;
#pragma unroll
      for (int j = 0; j < 8; j++)
        acc[j] = fmaf(__half2float(U.hh[j]), ex, acc[j]);  // v_fma_mix_f32
    }
  }

#pragma unroll
  for (int j = 0; j < 8; j++) {
    acc[j] += __shfl_xor(acc[j], 8);
    acc[j] += __shfl_xor(acc[j], 16);
    acc[j] += __shfl_xor(acc[j], 32);
  }
  den += __shfl_xor(den, 8);
  den += __shfl_xor(den, 16);
  den += __shfl_xor(den, 32);

  if (g == 0) {
    bool has = den > 0.f;
    float inv = has ? __builtin_amdgcn_rcpf(den) : 0.f;
    float4 r0, r1;
    r0.x = fmaxf(has ? 2.f * hd0.x - acc[0] * inv : hd0.x, 0.f);
    r0.y = fmaxf(has ? 2.f * hd0.y - acc[1] * inv : hd0.y, 0.f);
    r0.z = fmaxf(has ? 2.f * hd0.z - acc[2] * inv : hd0.z, 0.f);
    r0.w = fmaxf(has ? 2.f * hd0.w - acc[3] * inv : hd0.w, 0.f);
    r1.x = fmaxf(has ? 2.f * hd1.x - acc[4] * inv : hd1.x, 0.f);
    r1.y = fmaxf(has ? 2.f * hd1.y - acc[5] * inv : hd1.y, 0.f);
    r1.z = fmaxf(has ? 2.f * hd1.z - acc[6] * inv : hd1.z, 0.f);
    r1.w = fmaxf(has ? 2.f * hd1.w - acc[7] * inv : hd1.w, 0.f);
    float4* o4 = (float4*)out;
    o4[(size_t)n * (OUT_DIM / 4) + l8 * 2] = r0;
    o4[(size_t)n * (OUT_DIM / 4) + l8 * 2 + 1] = r1;
  }
}

extern "C" void kernel_launch(void* const* d_in, const int* in_sizes, int n_in,
                              void* d_out, int out_size, void* d_ws,
                              size_t ws_size, hipStream_t stream) {
  const float* h_init = (const float*)d_in[0];
  const float* W1 = (const float*)d_in[1];
  const float* a = (const float*)d_in[2];
  const int* src = (const int*)d_in[3];
  const int* dst = (const int*)d_in[4];
  float* out = (float*)d_out;

  // workspace layout (~62 MB)
  float* h = (float*)d_ws;                                    // 6.4M floats
  __half* h16 = (__half*)(h + (size_t)N_NODES * OUT_DIM);     // 6.4M halfs
  float* ha = (float*)(h16 + (size_t)N_NODES * OUT_DIM);      // 100K floats
  unsigned int* pairs = (unsigned int*)(ha + N_NODES);        // NBUCK*MAXB u32
  int2* sorted = (int2*)(pairs + (size_t)NBUCK * MAXB);       // NBUCK*MAXB int2
  int* nbeg = (int*)(sorted + (size_t)NBUCK * MAXB);          // 100K
  int* nend = nbeg + N_NODES;                                 // 100K
  int* bucket_cursor = nend + N_NODES;                        // 391

  hipMemsetAsync(bucket_cursor, 0, NBUCK * sizeof(int), stream);
  fat1_kernel<<<BIN_NBLK + PROJ_BLKS, 256, 0, stream>>>(
      h_init, W1, a, src, dst, h, h16, ha, bucket_cursor, pairs);
  bucket_sort_kernel<<<NBUCK, SORT_THREADS, 0, stream>>>(
      pairs, bucket_cursor, ha, nbeg, nend, sorted);
  gather_kernel<<<(N_NODES * 64 + 255) / 256, 256, 0, stream>>>(
      h, h16, nbeg, nend, sorted, out);
}